// Round 9
// baseline (131.226 us; speedup 1.0000x reference)
//
#include <hip/hip_runtime.h>

// ---------------- types & helpers (NO inline asm anywhere) ----------------
using short8 = __attribute__((ext_vector_type(8))) short;   // 8 x bf16 (4 VGPRs)
using f32x4  = __attribute__((ext_vector_type(4))) float;
using u16x4  = __attribute__((ext_vector_type(4))) unsigned short;

#define MFMA16(A,B,C) __builtin_amdgcn_mfma_f32_16x16x32_bf16((A),(B),(C),0,0,0)

#if __has_builtin(__builtin_amdgcn_exp2f)
#define EXP2(x) __builtin_amdgcn_exp2f(x)
#else
#define EXP2(x) exp2f(x)
#endif

__device__ __forceinline__ unsigned short f2b(float f) {
  unsigned u = __float_as_uint(f);
  return (unsigned short)((u + 0x7fffu + ((u >> 16) & 1u)) >> 16);  // RNE
}

// 8 consecutive f32 -> bf16x8 fragment (optional scale, pure VALU)
__device__ __forceinline__ short8 w8s(const float* p, float s) {
  const f32x4* q = (const f32x4*)p;
  f32x4 a = q[0], b = q[1];
  short8 r;
  r[0]=(short)f2b(a[0]*s); r[1]=(short)f2b(a[1]*s); r[2]=(short)f2b(a[2]*s); r[3]=(short)f2b(a[3]*s);
  r[4]=(short)f2b(b[0]*s); r[5]=(short)f2b(b[1]*s); r[6]=(short)f2b(b[2]*s); r[7]=(short)f2b(b[3]*s);
  return r;
}

// T=512, N=128, D=64, H=4, HID=OUT=64

// ---------------- kernel 1: xin = x + pe, transpose to [n][t][d] bf16 (r7-exact) ----------------
__global__ void prep_kernel(const float* __restrict__ x, const float* __restrict__ pe,
                            unsigned* __restrict__ xinT) {
  int i2 = blockIdx.x * 256 + threadIdx.x;      // handles elements 2*i2, 2*i2+1
  const float2* xp = (const float2*)x;
  const float2* pp = (const float2*)pe;
  float2 a = xp[i2], b = pp[i2];
  float s0 = a.x + b.x, s1 = a.y + b.y;
  int i   = i2 << 1;
  int t   = i >> 13;          // / (N*D=8192)
  int rem = i & 8191;
  int n   = rem >> 6;
  int d   = rem & 63;
  unsigned v = (unsigned)f2b(s0) | ((unsigned)f2b(s1) << 16);
  xinT[((n * 512 + t) * 64 + d) >> 1] = v;
}

// ---------------- kernel 2: fused QKV + causal flash attention ----------------
// 16 waves/block (4 waves/SIMD), LDS = 64K sK + 64K sVf = 128 KiB (proven < 147456).
// Per-wave transpose scratch is TIME-MULTIPLEXED onto the big buffers:
//   phase 0: Q-proj, scratch carved from sVf (not yet staged)   -> barrier
//   phase 1: stage K (swizzled) + V (kappa2 fragments)          -> barrier
//   phase 2: slab loop (bit-proven r7/r8 math)                  -> barrier
//   phase 3: epilogue, scratch carved from sK (dead now)
__global__ __launch_bounds__(1024) void attn_kernel(
    const unsigned short* __restrict__ xinT,
    const float* __restrict__ wq, const float* __restrict__ wk,
    const float* __restrict__ wv, unsigned short* __restrict__ heads) {
  __shared__ unsigned short sK[512 * 64];       // 64 KiB, XOR-swizzled
  __shared__ short8 sVf[16 * 4 * 64];           // 64 KiB kappa2 V fragments

  const int hn = blockIdx.x;
  const int h  = hn & 3;
  const int n  = hn >> 2;
  const int w  = threadIdx.x >> 6;    // 0..15
  const int l  = threadIdx.x & 63;
  const int lg = l >> 4;
  const int lm = l & 15;

  const unsigned short* xn = xinT + n * (512 * 64);
  const f32x4 zero4 = {0.f, 0.f, 0.f, 0.f};
  const float SC = 0.18033688011112042f;   // (1/sqrt(64)) * log2(e)

  // one chunk per wave, SIMD-balanced: s=w&3, j=w>>2 -> {s, 7-s, 8+s, 15-s}
  const int s4 = w & 3, jj = w >> 2;
  const int chunk = (jj == 0) ? s4 : (jj == 1) ? 7 - s4 : (jj == 2) ? 8 + s4 : 15 - s4;
  const int qb = chunk * 32;

  // ---- phase 0: Q projection (scratch = 2 KiB carve of sVf; sVf not staged yet) ----
  short8 qB[2][2];
  {
    short8 wqB[4][2];
    const float* bq = wq + h * 64 * 64;
#pragma unroll
    for (int nt = 0; nt < 4; ++nt)
#pragma unroll
      for (int ks = 0; ks < 2; ++ks)
        wqB[nt][ks] = w8s(bq + (nt * 16 + lm) * 64 + ks * 32 + lg * 8, SC);

    unsigned short* sQw = (unsigned short*)(sVf + (w << 7));   // 128 short8 = 2 KiB per wave
#pragma unroll
    for (int mt = 0; mt < 2; ++mt) {
      int r0 = qb + mt * 16;
      short8 aX0 = *(const short8*)(xn + (r0 + lm) * 64 + lg * 8);
      short8 aX1 = *(const short8*)(xn + (r0 + lm) * 64 + 32 + lg * 8);
#pragma unroll
      for (int nt = 0; nt < 4; ++nt) {
        f32x4 acc = zero4;
        acc = MFMA16(aX0, wqB[nt][0], acc);
        acc = MFMA16(aX1, wqB[nt][1], acc);
#pragma unroll
        for (int r = 0; r < 4; ++r) {
          int qr = lg * 4 + r;          // local 0..15
          int e  = nt * 16 + lm;
          sQw[qr * 64 + (e ^ ((qr & 7) << 3))] = f2b(acc[r]);
        }
      }
#pragma unroll
      for (int ks = 0; ks < 2; ++ks)
        qB[mt][ks] = *(const short8*)&sQw[lm * 64 + ((ks * 32 + lg * 8) ^ ((lm & 7) << 3))];
    }
  }
  __syncthreads();   // Q fragments extracted; sVf free for staging

  // ---- phase 1: stage K (swizzled) and V (kappa2 fragments); wave w: slab w ----
  {
    short8 wkB[4][2], wvB[4][2];
    const float* bk = wk + h * 64 * 64;
    const float* bv = wv + h * 64 * 64;
#pragma unroll
    for (int nt = 0; nt < 4; ++nt)
#pragma unroll
      for (int ks = 0; ks < 2; ++ks) {
        int off = (nt * 16 + lm) * 64 + ks * 32 + lg * 8;
        wkB[nt][ks] = w8s(bk + off, 1.0f);
        wvB[nt][ks] = w8s(bv + off, 1.0f);
      }

    int s0 = w * 32;                   // wave w stages 32-row slab w
    short8 aX[2][2];
#pragma unroll
    for (int km = 0; km < 2; ++km) {
      aX[km][0] = *(const short8*)(xn + (s0 + km * 16 + lm) * 64 + lg * 8);
      aX[km][1] = *(const short8*)(xn + (s0 + km * 16 + lm) * 64 + 32 + lg * 8);
    }
#pragma unroll
    for (int nt = 0; nt < 4; ++nt) {
      f32x4 k0 = zero4, k1 = zero4, v0 = zero4, v1 = zero4;
      k0 = MFMA16(aX[0][0], wkB[nt][0], k0); k0 = MFMA16(aX[0][1], wkB[nt][1], k0);
      k1 = MFMA16(aX[1][0], wkB[nt][0], k1); k1 = MFMA16(aX[1][1], wkB[nt][1], k1);
      v0 = MFMA16(aX[0][0], wvB[nt][0], v0); v0 = MFMA16(aX[0][1], wvB[nt][1], v0);
      v1 = MFMA16(aX[1][0], wvB[nt][0], v1); v1 = MFMA16(aX[1][1], wvB[nt][1], v1);
      // K[s][e] swizzled scatter (r7-exact)
#pragma unroll
      for (int r = 0; r < 4; ++r) {
        int row0 = s0 + lg * 4 + r;
        int row1 = s0 + 16 + lg * 4 + r;
        int e    = nt * 16 + lm;
        sK[row0 * 64 + (e ^ ((row0 & 7) << 3))] = f2b(k0[r]);
        sK[row1 * 64 + (e ^ ((row1 & 7) << 3))] = f2b(k1[r]);
      }
      // V kappa2 fragment, stored lane-linear (r7-exact)
      short8 vv;
      vv[0]=(short)f2b(v0[0]); vv[1]=(short)f2b(v0[1]);
      vv[2]=(short)f2b(v0[2]); vv[3]=(short)f2b(v0[3]);
      vv[4]=(short)f2b(v1[0]); vv[5]=(short)f2b(v1[1]);
      vv[6]=(short)f2b(v1[2]); vv[7]=(short)f2b(v1[3]);
      sVf[(w * 4 + nt) * 64 + l] = vv;
    }
  }
  __syncthreads();   // K and V staged

  // ---- phase 2: slab loop (bit-proven r7 math) ----
  f32x4 oAcc[2][4];
#pragma unroll
  for (int mo = 0; mo < 2; ++mo)
#pragma unroll
    for (int ot = 0; ot < 4; ++ot) oAcc[mo][ot] = zero4;
  float ls0 = 0.f, ls1 = 0.f;   // per-lane partials; reduced once per chunk

  for (int kb = 0; kb <= qb; kb += 32) {
    short8 aK[2][2];
#pragma unroll
    for (int km = 0; km < 2; ++km)
#pragma unroll
      for (int ks = 0; ks < 2; ++ks) {
        int row = kb + km * 16 + lm;
        aK[km][ks] = *(const short8*)&sK[row * 64 + ((ks * 32 + lg * 8) ^ ((row & 7) << 3))];
      }
    // S^T = K . Q^T (scale pre-folded into Q)
    f32x4 st[2][2];
#pragma unroll
    for (int km = 0; km < 2; ++km)
#pragma unroll
      for (int qn = 0; qn < 2; ++qn) {
        f32x4 acc = zero4;
        acc = MFMA16(aK[km][0], qB[qn][0], acc);
        acc = MFMA16(aK[km][1], qB[qn][1], acc);
        st[km][qn] = acc;
      }
    if (kb == qb) {   // diagonal slab: causal mask -> exp2(-1e30) = 0
#pragma unroll
      for (int km = 0; km < 2; ++km)
#pragma unroll
        for (int qn = 0; qn < 2; ++qn)
#pragma unroll
          for (int r = 0; r < 4; ++r) {
            int key = km * 16 + lg * 4 + r, qr = qn * 16 + lm;
            if (key > qr) st[km][qn][r] = -1e30f;
          }
    }
    // P = exp2(st): bounded scores, no max subtraction
#pragma unroll
    for (int km = 0; km < 2; ++km)
#pragma unroll
      for (int r = 0; r < 4; ++r) {
        float e0 = EXP2(st[km][0][r]); st[km][0][r] = e0; ls0 += e0;
        float e1 = EXP2(st[km][1][r]); st[km][1][r] = e1; ls1 += e1;
      }
    // V fragments: verbatim kappa2 short8 from LDS
    short8 vB[4];
#pragma unroll
    for (int ot = 0; ot < 4; ++ot) vB[ot] = sVf[(((kb >> 5) * 4) + ot) * 64 + l];
    // P packs straight from st registers; O accumulates unrescaled
#pragma unroll
    for (int mo = 0; mo < 2; ++mo) {
      short8 pA;
#pragma unroll
      for (int i = 0; i < 8; ++i) pA[i] = (short)f2b(st[i >> 2][mo][i & 3]);
#pragma unroll
      for (int ot = 0; ot < 4; ++ot) oAcc[mo][ot] = MFMA16(pA, vB[ot], oAcc[mo][ot]);
    }
  }

  __syncthreads();   // all waves done reading sK/sVf; sK free for epilogue scratch

  // ---- phase 3: reduce ls, normalize, transpose via sK carve, coalesced store ----
  {
    unsigned short* sE = sK + (w << 10);   // 1024 u16 = 2 KiB per wave
    ls0 += __shfl_xor(ls0, 16); ls0 += __shfl_xor(ls0, 32);
    ls1 += __shfl_xor(ls1, 16); ls1 += __shfl_xor(ls1, 32);
    float lsv[2] = {ls0, ls1};
#pragma unroll
    for (int mo = 0; mo < 2; ++mo) {
      float li[4];
#pragma unroll
      for (int r = 0; r < 4; ++r) li[r] = 1.0f / __shfl(lsv[mo], lg * 4 + r);
#pragma unroll
      for (int ot = 0; ot < 4; ++ot)
#pragma unroll
        for (int r = 0; r < 4; ++r) {
          int qr = lg * 4 + r;          // local 0..15
          int e  = ot * 16 + lm;
          sE[qr * 64 + (e ^ ((qr & 7) << 3))] = f2b(oAcc[mo][ot][r] * li[r]);
        }
#pragma unroll
      for (int j2 = 0; j2 < 4; ++j2) {
        int tl = j2 * 4 + lg;           // local 0..15
        int ob = lm * 4;
        u16x4 v = *(const u16x4*)&sE[tl * 64 + (ob ^ ((tl & 7) << 3))];
        int t = qb + mo * 16 + tl;
        *(u16x4*)&heads[(t * 128 + n) * 256 + h * 64 + ob] = v;
      }
    }
  }
}

// ---------------- kernel 3: out = heads[65536,256] @ wo^T (r7-exact) ----------------
__global__ __launch_bounds__(256) void outproj_kernel(
    const unsigned short* __restrict__ heads,
    const float* __restrict__ wo,
    float* __restrict__ out) {
  const int w  = threadIdx.x >> 6;
  const int l  = threadIdx.x & 63;
  const int lg = l >> 4, lm = l & 15;
  const f32x4 zero4 = {0.f, 0.f, 0.f, 0.f};

  short8 woB[4][8];   // B[k=c][n=o'] = wo[o'][c]
#pragma unroll
  for (int nt = 0; nt < 4; ++nt)
#pragma unroll
    for (int ks = 0; ks < 8; ++ks)
      woB[nt][ks] = w8s(wo + (nt * 16 + lm) * 256 + ks * 32 + lg * 8, 1.0f);

  const int wid = blockIdx.x * 4 + w;
  for (int it = 0; it < 2; ++it) {
    int r0 = (wid * 2 + it) * 16;
    f32x4 acc[4];
#pragma unroll
    for (int nt = 0; nt < 4; ++nt) acc[nt] = zero4;
#pragma unroll
    for (int ks = 0; ks < 8; ++ks) {
      short8 aF = *(const short8*)&heads[(r0 + lm) * 256 + ks * 32 + lg * 8];
#pragma unroll
      for (int nt = 0; nt < 4; ++nt)
        acc[nt] = MFMA16(aF, woB[nt][ks], acc[nt]);
    }
#pragma unroll
    for (int nt = 0; nt < 4; ++nt)
#pragma unroll
      for (int r = 0; r < 4; ++r)
        out[(r0 + lg * 4 + r) * 64 + nt * 16 + lm] = acc[nt][r];
  }
}

// ---------------- launch (r7-exact ws layout) ----------------
extern "C" void kernel_launch(void* const* d_in, const int* in_sizes, int n_in,
                              void* d_out, int out_size, void* d_ws, size_t ws_size,
                              hipStream_t stream) {
  const float* x  = (const float*)d_in[0];
  const float* pe = (const float*)d_in[1];
  const float* wq = (const float*)d_in[2];
  const float* wk = (const float*)d_in[3];
  const float* wv = (const float*)d_in[4];
  const float* wo = (const float*)d_in[5];

  unsigned short* xinT  = (unsigned short*)d_ws;                          // 8 MiB  [n][t][d]
  unsigned short* heads = (unsigned short*)((char*)d_ws + (16u << 20));   // 32 MiB [t][n][256]

  prep_kernel<<<8192, 256, 0, stream>>>(x, pe, (unsigned*)xinT);
  attn_kernel<<<512, 1024, 0, stream>>>(xinT, wq, wk, wv, heads);
  outproj_kernel<<<512, 256, 0, stream>>>(heads, wo, (float*)d_out);
}

// Round 10
// 130.988 us; speedup vs baseline: 1.0018x; 1.0018x over previous
//
#include <hip/hip_runtime.h>

// ---------------- types & helpers (NO inline asm anywhere) ----------------
using short8 = __attribute__((ext_vector_type(8))) short;   // 8 x bf16 (4 VGPRs)
using f32x4  = __attribute__((ext_vector_type(4))) float;
using u16x4  = __attribute__((ext_vector_type(4))) unsigned short;

#define MFMA16(A,B,C) __builtin_amdgcn_mfma_f32_16x16x32_bf16((A),(B),(C),0,0,0)

#if __has_builtin(__builtin_amdgcn_exp2f)
#define EXP2(x) __builtin_amdgcn_exp2f(x)
#else
#define EXP2(x) exp2f(x)
#endif

__device__ __forceinline__ unsigned short f2b(float f) {
  unsigned u = __float_as_uint(f);
  return (unsigned short)((u + 0x7fffu + ((u >> 16) & 1u)) >> 16);  // RNE
}

// 8 consecutive f32 -> bf16x8 fragment (optional scale, pure VALU)
__device__ __forceinline__ short8 w8s(const float* p, float s) {
  const f32x4* q = (const f32x4*)p;
  f32x4 a = q[0], b = q[1];
  short8 r;
  r[0]=(short)f2b(a[0]*s); r[1]=(short)f2b(a[1]*s); r[2]=(short)f2b(a[2]*s); r[3]=(short)f2b(a[3]*s);
  r[4]=(short)f2b(b[0]*s); r[5]=(short)f2b(b[1]*s); r[6]=(short)f2b(b[2]*s); r[7]=(short)f2b(b[3]*s);
  return r;
}

// T=512, N=128, D=64, H=4, HID=OUT=64

// ---------------- kernel 1: xin = x + pe, transpose to [n][t][d] bf16 (r9-exact) ----------------
__global__ void prep_kernel(const float* __restrict__ x, const float* __restrict__ pe,
                            unsigned* __restrict__ xinT) {
  int i2 = blockIdx.x * 256 + threadIdx.x;      // handles elements 2*i2, 2*i2+1
  const float2* xp = (const float2*)x;
  const float2* pp = (const float2*)pe;
  float2 a = xp[i2], b = pp[i2];
  float s0 = a.x + b.x, s1 = a.y + b.y;
  int i   = i2 << 1;
  int t   = i >> 13;          // / (N*D=8192)
  int rem = i & 8191;
  int n   = rem >> 6;
  int d   = rem & 63;
  unsigned v = (unsigned)f2b(s0) | ((unsigned)f2b(s1) << 16);
  xinT[((n * 512 + t) * 64 + d) >> 1] = v;
}

// ---------------- kernel 2: fused QKV + causal flash attention ----------------
// r9 structure (proven correct), with __launch_bounds__(1024, 4):
// min 4 waves/EU -> VGPR cap 128 -> NO SPILL (r9's plain (1024) defaulted to
// a 64-VGPR cap and spilled ~150 MB/dispatch to scratch).
//   phase 0: Q-proj, scratch carved from sVf (not yet staged)   -> barrier
//   phase 1: stage K (swizzled) + V (kappa2 fragments)          -> barrier
//   phase 2: slab loop (bit-proven math)                        -> barrier
//   phase 3: epilogue, scratch carved from sK (dead now)
__global__ __launch_bounds__(1024, 4) void attn_kernel(
    const unsigned short* __restrict__ xinT,
    const float* __restrict__ wq, const float* __restrict__ wk,
    const float* __restrict__ wv, unsigned short* __restrict__ heads) {
  __shared__ unsigned short sK[512 * 64];       // 64 KiB, XOR-swizzled
  __shared__ short8 sVf[16 * 4 * 64];           // 64 KiB kappa2 V fragments

  const int hn = blockIdx.x;
  const int h  = hn & 3;
  const int n  = hn >> 2;
  const int w  = threadIdx.x >> 6;    // 0..15
  const int l  = threadIdx.x & 63;
  const int lg = l >> 4;
  const int lm = l & 15;

  const unsigned short* xn = xinT + n * (512 * 64);
  const f32x4 zero4 = {0.f, 0.f, 0.f, 0.f};
  const float SC = 0.18033688011112042f;   // (1/sqrt(64)) * log2(e)

  // one chunk per wave, SIMD-balanced: s=w&3, j=w>>2 -> {s, 7-s, 8+s, 15-s}
  const int s4 = w & 3, jj = w >> 2;
  const int chunk = (jj == 0) ? s4 : (jj == 1) ? 7 - s4 : (jj == 2) ? 8 + s4 : 15 - s4;
  const int qb = chunk * 32;

  // ---- phase 0: Q projection (scratch = 2 KiB carve of sVf; sVf not staged yet) ----
  short8 qB[2][2];
  {
    short8 wqB[4][2];
    const float* bq = wq + h * 64 * 64;
#pragma unroll
    for (int nt = 0; nt < 4; ++nt)
#pragma unroll
      for (int ks = 0; ks < 2; ++ks)
        wqB[nt][ks] = w8s(bq + (nt * 16 + lm) * 64 + ks * 32 + lg * 8, SC);

    unsigned short* sQw = (unsigned short*)(sVf + (w << 7));   // 128 short8 = 2 KiB per wave
#pragma unroll
    for (int mt = 0; mt < 2; ++mt) {
      int r0 = qb + mt * 16;
      short8 aX0 = *(const short8*)(xn + (r0 + lm) * 64 + lg * 8);
      short8 aX1 = *(const short8*)(xn + (r0 + lm) * 64 + 32 + lg * 8);
#pragma unroll
      for (int nt = 0; nt < 4; ++nt) {
        f32x4 acc = zero4;
        acc = MFMA16(aX0, wqB[nt][0], acc);
        acc = MFMA16(aX1, wqB[nt][1], acc);
#pragma unroll
        for (int r = 0; r < 4; ++r) {
          int qr = lg * 4 + r;          // local 0..15
          int e  = nt * 16 + lm;
          sQw[qr * 64 + (e ^ ((qr & 7) << 3))] = f2b(acc[r]);
        }
      }
#pragma unroll
      for (int ks = 0; ks < 2; ++ks)
        qB[mt][ks] = *(const short8*)&sQw[lm * 64 + ((ks * 32 + lg * 8) ^ ((lm & 7) << 3))];
    }
  }
  __syncthreads();   // Q fragments extracted; sVf free for staging

  // ---- phase 1: stage K (swizzled) and V (kappa2 fragments); wave w: slab w ----
  {
    short8 wkB[4][2], wvB[4][2];
    const float* bk = wk + h * 64 * 64;
    const float* bv = wv + h * 64 * 64;
#pragma unroll
    for (int nt = 0; nt < 4; ++nt)
#pragma unroll
      for (int ks = 0; ks < 2; ++ks) {
        int off = (nt * 16 + lm) * 64 + ks * 32 + lg * 8;
        wkB[nt][ks] = w8s(bk + off, 1.0f);
        wvB[nt][ks] = w8s(bv + off, 1.0f);
      }

    int s0 = w * 32;                   // wave w stages 32-row slab w
    short8 aX[2][2];
#pragma unroll
    for (int km = 0; km < 2; ++km) {
      aX[km][0] = *(const short8*)(xn + (s0 + km * 16 + lm) * 64 + lg * 8);
      aX[km][1] = *(const short8*)(xn + (s0 + km * 16 + lm) * 64 + 32 + lg * 8);
    }
#pragma unroll
    for (int nt = 0; nt < 4; ++nt) {
      f32x4 k0 = zero4, k1 = zero4, v0 = zero4, v1 = zero4;
      k0 = MFMA16(aX[0][0], wkB[nt][0], k0); k0 = MFMA16(aX[0][1], wkB[nt][1], k0);
      k1 = MFMA16(aX[1][0], wkB[nt][0], k1); k1 = MFMA16(aX[1][1], wkB[nt][1], k1);
      v0 = MFMA16(aX[0][0], wvB[nt][0], v0); v0 = MFMA16(aX[0][1], wvB[nt][1], v0);
      v1 = MFMA16(aX[1][0], wvB[nt][0], v1); v1 = MFMA16(aX[1][1], wvB[nt][1], v1);
      // K[s][e] swizzled scatter (r9-exact)
#pragma unroll
      for (int r = 0; r < 4; ++r) {
        int row0 = s0 + lg * 4 + r;
        int row1 = s0 + 16 + lg * 4 + r;
        int e    = nt * 16 + lm;
        sK[row0 * 64 + (e ^ ((row0 & 7) << 3))] = f2b(k0[r]);
        sK[row1 * 64 + (e ^ ((row1 & 7) << 3))] = f2b(k1[r]);
      }
      // V kappa2 fragment, stored lane-linear (r9-exact)
      short8 vv;
      vv[0]=(short)f2b(v0[0]); vv[1]=(short)f2b(v0[1]);
      vv[2]=(short)f2b(v0[2]); vv[3]=(short)f2b(v0[3]);
      vv[4]=(short)f2b(v1[0]); vv[5]=(short)f2b(v1[1]);
      vv[6]=(short)f2b(v1[2]); vv[7]=(short)f2b(v1[3]);
      sVf[(w * 4 + nt) * 64 + l] = vv;
    }
  }
  __syncthreads();   // K and V staged

  // ---- phase 2: slab loop (bit-proven math) ----
  f32x4 oAcc[2][4];
#pragma unroll
  for (int mo = 0; mo < 2; ++mo)
#pragma unroll
    for (int ot = 0; ot < 4; ++ot) oAcc[mo][ot] = zero4;
  float ls0 = 0.f, ls1 = 0.f;   // per-lane partials; reduced once per chunk

  for (int kb = 0; kb <= qb; kb += 32) {
    short8 aK[2][2];
#pragma unroll
    for (int km = 0; km < 2; ++km)
#pragma unroll
      for (int ks = 0; ks < 2; ++ks) {
        int row = kb + km * 16 + lm;
        aK[km][ks] = *(const short8*)&sK[row * 64 + ((ks * 32 + lg * 8) ^ ((row & 7) << 3))];
      }
    // S^T = K . Q^T (scale pre-folded into Q)
    f32x4 st[2][2];
#pragma unroll
    for (int km = 0; km < 2; ++km)
#pragma unroll
      for (int qn = 0; qn < 2; ++qn) {
        f32x4 acc = zero4;
        acc = MFMA16(aK[km][0], qB[qn][0], acc);
        acc = MFMA16(aK[km][1], qB[qn][1], acc);
        st[km][qn] = acc;
      }
    if (kb == qb) {   // diagonal slab: causal mask -> exp2(-1e30) = 0
#pragma unroll
      for (int km = 0; km < 2; ++km)
#pragma unroll
        for (int qn = 0; qn < 2; ++qn)
#pragma unroll
          for (int r = 0; r < 4; ++r) {
            int key = km * 16 + lg * 4 + r, qr = qn * 16 + lm;
            if (key > qr) st[km][qn][r] = -1e30f;
          }
    }
    // P = exp2(st): bounded scores, no max subtraction
#pragma unroll
    for (int km = 0; km < 2; ++km)
#pragma unroll
      for (int r = 0; r < 4; ++r) {
        float e0 = EXP2(st[km][0][r]); st[km][0][r] = e0; ls0 += e0;
        float e1 = EXP2(st[km][1][r]); st[km][1][r] = e1; ls1 += e1;
      }
    // V fragments: verbatim kappa2 short8 from LDS
    short8 vB[4];
#pragma unroll
    for (int ot = 0; ot < 4; ++ot) vB[ot] = sVf[(((kb >> 5) * 4) + ot) * 64 + l];
    // P packs straight from st registers; O accumulates unrescaled
#pragma unroll
    for (int mo = 0; mo < 2; ++mo) {
      short8 pA;
#pragma unroll
      for (int i = 0; i < 8; ++i) pA[i] = (short)f2b(st[i >> 2][mo][i & 3]);
#pragma unroll
      for (int ot = 0; ot < 4; ++ot) oAcc[mo][ot] = MFMA16(pA, vB[ot], oAcc[mo][ot]);
    }
  }

  __syncthreads();   // all waves done reading sK/sVf; sK free for epilogue scratch

  // ---- phase 3: reduce ls, normalize, transpose via sK carve, coalesced store ----
  {
    unsigned short* sE = sK + (w << 10);   // 1024 u16 = 2 KiB per wave
    ls0 += __shfl_xor(ls0, 16); ls0 += __shfl_xor(ls0, 32);
    ls1 += __shfl_xor(ls1, 16); ls1 += __shfl_xor(ls1, 32);
    float lsv[2] = {ls0, ls1};
#pragma unroll
    for (int mo = 0; mo < 2; ++mo) {
      float li[4];
#pragma unroll
      for (int r = 0; r < 4; ++r) li[r] = 1.0f / __shfl(lsv[mo], lg * 4 + r);
#pragma unroll
      for (int ot = 0; ot < 4; ++ot)
#pragma unroll
        for (int r = 0; r < 4; ++r) {
          int qr = lg * 4 + r;          // local 0..15
          int e  = ot * 16 + lm;
          sE[qr * 64 + (e ^ ((qr & 7) << 3))] = f2b(oAcc[mo][ot][r] * li[r]);
        }
#pragma unroll
      for (int j2 = 0; j2 < 4; ++j2) {
        int tl = j2 * 4 + lg;           // local 0..15
        int ob = lm * 4;
        u16x4 v = *(const u16x4*)&sE[tl * 64 + (ob ^ ((tl & 7) << 3))];
        int t = qb + mo * 16 + tl;
        *(u16x4*)&heads[(t * 128 + n) * 256 + h * 64 + ob] = v;
      }
    }
  }
}

// ---------------- kernel 3: out = heads[65536,256] @ wo^T (r9-exact) ----------------
__global__ __launch_bounds__(256) void outproj_kernel(
    const unsigned short* __restrict__ heads,
    const float* __restrict__ wo,
    float* __restrict__ out) {
  const int w  = threadIdx.x >> 6;
  const int l  = threadIdx.x & 63;
  const int lg = l >> 4, lm = l & 15;
  const f32x4 zero4 = {0.f, 0.f, 0.f, 0.f};

  short8 woB[4][8];   // B[k=c][n=o'] = wo[o'][c]
#pragma unroll
  for (int nt = 0; nt < 4; ++nt)
#pragma unroll
    for (int ks = 0; ks < 8; ++ks)
      woB[nt][ks] = w8s(wo + (nt * 16 + lm) * 256 + ks * 32 + lg * 8, 1.0f);

  const int wid = blockIdx.x * 4 + w;
  for (int it = 0; it < 2; ++it) {
    int r0 = (wid * 2 + it) * 16;
    f32x4 acc[4];
#pragma unroll
    for (int nt = 0; nt < 4; ++nt) acc[nt] = zero4;
#pragma unroll
    for (int ks = 0; ks < 8; ++ks) {
      short8 aF = *(const short8*)&heads[(r0 + lm) * 256 + ks * 32 + lg * 8];
#pragma unroll
      for (int nt = 0; nt < 4; ++nt)
        acc[nt] = MFMA16(aF, woB[nt][ks], acc[nt]);
    }
#pragma unroll
    for (int nt = 0; nt < 4; ++nt)
#pragma unroll
      for (int r = 0; r < 4; ++r)
        out[(r0 + lg * 4 + r) * 64 + nt * 16 + lm] = acc[nt][r];
  }
}

// ---------------- launch (r9-exact ws layout) ----------------
extern "C" void kernel_launch(void* const* d_in, const int* in_sizes, int n_in,
                              void* d_out, int out_size, void* d_ws, size_t ws_size,
                              hipStream_t stream) {
  const float* x  = (const float*)d_in[0];
  const float* pe = (const float*)d_in[1];
  const float* wq = (const float*)d_in[2];
  const float* wk = (const float*)d_in[3];
  const float* wv = (const float*)d_in[4];
  const float* wo = (const float*)d_in[5];

  unsigned short* xinT  = (unsigned short*)d_ws;                          // 8 MiB  [n][t][d]
  unsigned short* heads = (unsigned short*)((char*)d_ws + (16u << 20));   // 32 MiB [t][n][256]

  prep_kernel<<<8192, 256, 0, stream>>>(x, pe, (unsigned*)xinT);
  attn_kernel<<<512, 1024, 0, stream>>>(xinT, wq, wk, wv, heads);
  outproj_kernel<<<512, 256, 0, stream>>>(heads, wo, (float*)d_out);
}

// Round 11
// 114.390 us; speedup vs baseline: 1.1472x; 1.1451x over previous
//
#include <hip/hip_runtime.h>

// ---------------- types & helpers (NO inline asm anywhere) ----------------
using short8 = __attribute__((ext_vector_type(8))) short;   // 8 x bf16 (4 VGPRs)
using f32x4  = __attribute__((ext_vector_type(4))) float;
using u16x4  = __attribute__((ext_vector_type(4))) unsigned short;

#define MFMA16(A,B,C) __builtin_amdgcn_mfma_f32_16x16x32_bf16((A),(B),(C),0,0,0)

#if __has_builtin(__builtin_amdgcn_exp2f)
#define EXP2(x) __builtin_amdgcn_exp2f(x)
#else
#define EXP2(x) exp2f(x)
#endif

__device__ __forceinline__ unsigned short f2b(float f) {
  unsigned u = __float_as_uint(f);
  return (unsigned short)((u + 0x7fffu + ((u >> 16) & 1u)) >> 16);  // RNE
}

// 8 consecutive f32 -> bf16x8 fragment (optional scale, pure VALU)
__device__ __forceinline__ short8 w8s(const float* p, float s) {
  const f32x4* q = (const f32x4*)p;
  f32x4 a = q[0], b = q[1];
  short8 r;
  r[0]=(short)f2b(a[0]*s); r[1]=(short)f2b(a[1]*s); r[2]=(short)f2b(a[2]*s); r[3]=(short)f2b(a[3]*s);
  r[4]=(short)f2b(b[0]*s); r[5]=(short)f2b(b[1]*s); r[6]=(short)f2b(b[2]*s); r[7]=(short)f2b(b[3]*s);
  return r;
}

// T=512, N=128, D=64, H=4, HID=OUT=64

// ---------------- kernel 1: xin = x + pe, transpose to [n][t][d] bf16 (r10-exact) ----------------
__global__ void prep_kernel(const float* __restrict__ x, const float* __restrict__ pe,
                            unsigned* __restrict__ xinT) {
  int i2 = blockIdx.x * 256 + threadIdx.x;      // handles elements 2*i2, 2*i2+1
  const float2* xp = (const float2*)x;
  const float2* pp = (const float2*)pe;
  float2 a = xp[i2], b = pp[i2];
  float s0 = a.x + b.x, s1 = a.y + b.y;
  int i   = i2 << 1;
  int t   = i >> 13;          // / (N*D=8192)
  int rem = i & 8191;
  int n   = rem >> 6;
  int d   = rem & 63;
  unsigned v = (unsigned)f2b(s0) | ((unsigned)f2b(s1) << 16);
  xinT[((n * 512 + t) * 64 + d) >> 1] = v;
}

// ---------------- attn building blocks ----------------
// Q projection for 16 rows at qb16 -> qB fragments (via per-wave swizzled scratch)
__device__ __forceinline__ void qproj16(
    const unsigned short* xn, const short8 (&wqB)[4][2], unsigned short* sQw,
    int qb16, int lg, int lm, short8 (&qB)[2]) {
  const f32x4 zero4 = {0.f, 0.f, 0.f, 0.f};
  short8 aX0 = *(const short8*)(xn + (qb16 + lm) * 64 + lg * 8);
  short8 aX1 = *(const short8*)(xn + (qb16 + lm) * 64 + 32 + lg * 8);
#pragma unroll
  for (int nt = 0; nt < 4; ++nt) {
    f32x4 acc = zero4;
    acc = MFMA16(aX0, wqB[nt][0], acc);
    acc = MFMA16(aX1, wqB[nt][1], acc);
#pragma unroll
    for (int r = 0; r < 4; ++r) {
      int qr = lg * 4 + r;              // local 0..15
      int e  = nt * 16 + lm;
      sQw[qr * 64 + (e ^ ((qr & 7) << 3))] = f2b(acc[r]);
    }
  }
#pragma unroll
  for (int ks = 0; ks < 2; ++ks)
    qB[ks] = *(const short8*)&sQw[lm * 64 + ((ks * 32 + lg * 8) ^ ((lm & 7) << 3))];
}

// one 32-key slab step for one 16-row chunk (bit-identical math to r9/r10)
__device__ __forceinline__ void chunk_step(
    const short8 (&qB)[2], const short8 (&aK)[2][2], const short8 (&vB)[4],
    f32x4 (&oAcc)[4], float& ls, int qb16, int kb, int lg, int lm) {
  const f32x4 zero4 = {0.f, 0.f, 0.f, 0.f};
  f32x4 st[2];
#pragma unroll
  for (int km = 0; km < 2; ++km) {
    f32x4 a = zero4;
    a = MFMA16(aK[km][0], qB[0], a);
    a = MFMA16(aK[km][1], qB[1], a);
    st[km] = a;
  }
  if (kb + 32 > qb16) {                 // final (diagonal-crossing) slab
    int qrl = qb16 - kb + lm;           // local query row vs local key row
#pragma unroll
    for (int km = 0; km < 2; ++km)
#pragma unroll
      for (int r = 0; r < 4; ++r)
        if (km * 16 + lg * 4 + r > qrl) st[km][r] = -1e30f;
  }
#pragma unroll
  for (int km = 0; km < 2; ++km)
#pragma unroll
    for (int r = 0; r < 4; ++r) {
      float e = EXP2(st[km][r]); st[km][r] = e; ls += e;
    }
  short8 pA;
#pragma unroll
  for (int i = 0; i < 8; ++i) pA[i] = (short)f2b(st[i >> 2][i & 3]);
#pragma unroll
  for (int ot = 0; ot < 4; ++ot) oAcc[ot] = MFMA16(pA, vB[ot], oAcc[ot]);
}

// normalize + transpose (via scratch) + coalesced store for 16 rows at qb16
__device__ __forceinline__ void epilogue16(
    f32x4 (&oAcc)[4], float ls, unsigned short* sE, unsigned short* heads,
    int qb16, int n, int h, int lg, int lm) {
  ls += __shfl_xor(ls, 16); ls += __shfl_xor(ls, 32);
  float li[4];
#pragma unroll
  for (int r = 0; r < 4; ++r) li[r] = 1.0f / __shfl(ls, lg * 4 + r);
#pragma unroll
  for (int ot = 0; ot < 4; ++ot)
#pragma unroll
    for (int r = 0; r < 4; ++r) {
      int qr = lg * 4 + r;              // local 0..15
      int e  = ot * 16 + lm;
      sE[qr * 64 + (e ^ ((qr & 7) << 3))] = f2b(oAcc[ot][r] * li[r]);
    }
#pragma unroll
  for (int j2 = 0; j2 < 4; ++j2) {
    int tl = j2 * 4 + lg;               // local 0..15
    u16x4 v = *(const u16x4*)&sE[tl * 64 + ((lm * 4) ^ ((tl & 7) << 3))];
    int t = qb16 + tl;
    *(u16x4*)&heads[(t * 128 + n) * 256 + h * 64 + lm * 4] = v;
  }
}

// ---------------- kernel 2: fused QKV + causal flash attention ----------------
// 16 waves/block, LDS 128 KiB, VGPR budget pinned via amdgpu_waves_per_eu(4,4)
// (r10 showed __launch_bounds__(1024,4) is IGNORED: budget stayed 64 -> spill).
// 16-row Q chunks (2/wave, {w, 31-w}, fused slab loop sharing aK/vB reads)
// drop per-wave demand to ~100 regs so the 128 budget fits with zero spill.
//   phase 0: Q-proj both chunks, scratch carved from sVf      -> barrier
//   phase 1: stage K (swizzled) + V (kappa2 fragments)        -> barrier
//   phase 2: fused dual-chunk slab loop                       -> barrier
//   phase 3: epilogues, scratch carved from sK
__global__ __attribute__((amdgpu_flat_work_group_size(1024, 1024), amdgpu_waves_per_eu(4, 4)))
void attn_kernel(
    const unsigned short* __restrict__ xinT,
    const float* __restrict__ wq, const float* __restrict__ wk,
    const float* __restrict__ wv, unsigned short* __restrict__ heads) {
  __shared__ unsigned short sK[512 * 64];       // 64 KiB, XOR-swizzled
  __shared__ short8 sVf[16 * 4 * 64];           // 64 KiB kappa2 V fragments

  const int hn = blockIdx.x;
  const int h  = hn & 3;
  const int n  = hn >> 2;
  const int w  = threadIdx.x >> 6;    // 0..15
  const int l  = threadIdx.x & 63;
  const int lg = l >> 4;
  const int lm = l & 15;

  const unsigned short* xn = xinT + n * (512 * 64);
  const f32x4 zero4 = {0.f, 0.f, 0.f, 0.f};
  const float SC = 0.18033688011112042f;   // (1/sqrt(64)) * log2(e)

  // two 16-row chunks per wave: A = w (low), B = 31-w (high); 17 slab-steps total each
  const int qbA = w * 16;
  const int qbB = (31 - w) * 16;

  // ---- phase 0: Q projection for both chunks (scratch = 2 KiB carve of sVf) ----
  short8 qBA[2], qBB[2];
  {
    short8 wqB[4][2];
    const float* bq = wq + h * 64 * 64;
#pragma unroll
    for (int nt = 0; nt < 4; ++nt)
#pragma unroll
      for (int ks = 0; ks < 2; ++ks)
        wqB[nt][ks] = w8s(bq + (nt * 16 + lm) * 64 + ks * 32 + lg * 8, SC);

    unsigned short* sQw = (unsigned short*)(sVf + (w << 7));   // 2 KiB per wave
    qproj16(xn, wqB, sQw, qbA, lg, lm, qBA);
    qproj16(xn, wqB, sQw, qbB, lg, lm, qBB);
  }
  __syncthreads();   // Q fragments extracted; sVf free for staging

  // ---- phase 1: stage K (swizzled) and V (kappa2 fragments); wave w: slab w ----
  {
    const float* bk = wk + h * 64 * 64;
    const float* bv = wv + h * 64 * 64;
    int s0 = w * 32;                   // wave w stages 32-row slab w
    short8 aX[2][2];
#pragma unroll
    for (int km = 0; km < 2; ++km) {
      aX[km][0] = *(const short8*)(xn + (s0 + km * 16 + lm) * 64 + lg * 8);
      aX[km][1] = *(const short8*)(xn + (s0 + km * 16 + lm) * 64 + 32 + lg * 8);
    }
#pragma unroll
    for (int nt = 0; nt < 4; ++nt) {
      // per-nt weight fragments (caps phase-local register pressure)
      const float* bko = bk + (nt * 16 + lm) * 64 + lg * 8;
      const float* bvo = bv + (nt * 16 + lm) * 64 + lg * 8;
      short8 wk0 = w8s(bko, 1.0f), wk1 = w8s(bko + 32, 1.0f);
      short8 wv0 = w8s(bvo, 1.0f), wv1 = w8s(bvo + 32, 1.0f);
      f32x4 k0 = zero4, k1 = zero4, v0 = zero4, v1 = zero4;
      k0 = MFMA16(aX[0][0], wk0, k0); k0 = MFMA16(aX[0][1], wk1, k0);
      k1 = MFMA16(aX[1][0], wk0, k1); k1 = MFMA16(aX[1][1], wk1, k1);
      v0 = MFMA16(aX[0][0], wv0, v0); v0 = MFMA16(aX[0][1], wv1, v0);
      v1 = MFMA16(aX[1][0], wv0, v1); v1 = MFMA16(aX[1][1], wv1, v1);
      // K[s][e] swizzled scatter (r9-exact)
#pragma unroll
      for (int r = 0; r < 4; ++r) {
        int row0 = s0 + lg * 4 + r;
        int row1 = s0 + 16 + lg * 4 + r;
        int e    = nt * 16 + lm;
        sK[row0 * 64 + (e ^ ((row0 & 7) << 3))] = f2b(k0[r]);
        sK[row1 * 64 + (e ^ ((row1 & 7) << 3))] = f2b(k1[r]);
      }
      // V kappa2 fragment, stored lane-linear (r9-exact)
      short8 vv;
      vv[0]=(short)f2b(v0[0]); vv[1]=(short)f2b(v0[1]);
      vv[2]=(short)f2b(v0[2]); vv[3]=(short)f2b(v0[3]);
      vv[4]=(short)f2b(v1[0]); vv[5]=(short)f2b(v1[1]);
      vv[6]=(short)f2b(v1[2]); vv[7]=(short)f2b(v1[3]);
      sVf[(w * 4 + nt) * 64 + l] = vv;
    }
  }
  __syncthreads();   // K and V staged

  // ---- phase 2: fused dual-chunk slab loop (shared aK/vB reads) ----
  f32x4 oAccA[4], oAccB[4];
#pragma unroll
  for (int ot = 0; ot < 4; ++ot) { oAccA[ot] = zero4; oAccB[ot] = zero4; }
  float lsA = 0.f, lsB = 0.f;

  for (int kb = 0; kb <= qbB; kb += 32) {
    short8 aK[2][2];
#pragma unroll
    for (int km = 0; km < 2; ++km)
#pragma unroll
      for (int ks = 0; ks < 2; ++ks) {
        int row = kb + km * 16 + lm;
        aK[km][ks] = *(const short8*)&sK[row * 64 + ((ks * 32 + lg * 8) ^ ((row & 7) << 3))];
      }
    short8 vB[4];
#pragma unroll
    for (int ot = 0; ot < 4; ++ot) vB[ot] = sVf[(((kb >> 5) * 4) + ot) * 64 + l];

    if (kb <= qbA) chunk_step(qBA, aK, vB, oAccA, lsA, qbA, kb, lg, lm);
    chunk_step(qBB, aK, vB, oAccB, lsB, qbB, kb, lg, lm);
  }

  __syncthreads();   // all waves done reading sK/sVf; sK free for epilogue scratch

  // ---- phase 3: epilogues (scratch = 2 KiB carve of sK) ----
  {
    unsigned short* sE = sK + (w << 10);   // 1024 u16 = 2 KiB per wave
    epilogue16(oAccA, lsA, sE, heads, qbA, n, h, lg, lm);
    epilogue16(oAccB, lsB, sE, heads, qbB, n, h, lg, lm);
  }
}

// ---------------- kernel 3: out = heads[65536,256] @ wo^T (r10-exact) ----------------
__global__ __launch_bounds__(256) void outproj_kernel(
    const unsigned short* __restrict__ heads,
    const float* __restrict__ wo,
    float* __restrict__ out) {
  const int w  = threadIdx.x >> 6;
  const int l  = threadIdx.x & 63;
  const int lg = l >> 4, lm = l & 15;
  const f32x4 zero4 = {0.f, 0.f, 0.f, 0.f};

  short8 woB[4][8];   // B[k=c][n=o'] = wo[o'][c]
#pragma unroll
  for (int nt = 0; nt < 4; ++nt)
#pragma unroll
    for (int ks = 0; ks < 8; ++ks)
      woB[nt][ks] = w8s(wo + (nt * 16 + lm) * 256 + ks * 32 + lg * 8, 1.0f);

  const int wid = blockIdx.x * 4 + w;
  for (int it = 0; it < 2; ++it) {
    int r0 = (wid * 2 + it) * 16;
    f32x4 acc[4];
#pragma unroll
    for (int nt = 0; nt < 4; ++nt) acc[nt] = zero4;
#pragma unroll
    for (int ks = 0; ks < 8; ++ks) {
      short8 aF = *(const short8*)&heads[(r0 + lm) * 256 + ks * 32 + lg * 8];
#pragma unroll
      for (int nt = 0; nt < 4; ++nt)
        acc[nt] = MFMA16(aF, woB[nt][ks], acc[nt]);
    }
#pragma unroll
    for (int nt = 0; nt < 4; ++nt)
#pragma unroll
      for (int r = 0; r < 4; ++r)
        out[(r0 + lg * 4 + r) * 64 + nt * 16 + lm] = acc[nt][r];
  }
}

// ---------------- launch (r10-exact ws layout) ----------------
extern "C" void kernel_launch(void* const* d_in, const int* in_sizes, int n_in,
                              void* d_out, int out_size, void* d_ws, size_t ws_size,
                              hipStream_t stream) {
  const float* x  = (const float*)d_in[0];
  const float* pe = (const float*)d_in[1];
  const float* wq = (const float*)d_in[2];
  const float* wk = (const float*)d_in[3];
  const float* wv = (const float*)d_in[4];
  const float* wo = (const float*)d_in[5];

  unsigned short* xinT  = (unsigned short*)d_ws;                          // 8 MiB  [n][t][d]
  unsigned short* heads = (unsigned short*)((char*)d_ws + (16u << 20));   // 32 MiB [t][n][256]

  prep_kernel<<<8192, 256, 0, stream>>>(x, pe, (unsigned*)xinT);
  attn_kernel<<<512, 1024, 0, stream>>>(xinT, wq, wk, wv, heads);
  outproj_kernel<<<512, 256, 0, stream>>>(heads, wo, (float*)d_out);
}

// Round 12
// 88.647 us; speedup vs baseline: 1.4803x; 1.2904x over previous
//
#include <hip/hip_runtime.h>

// ---------------- types & helpers ----------------
using short8 = __attribute__((ext_vector_type(8))) short;   // 8 x bf16 (4 VGPRs)
using f32x4  = __attribute__((ext_vector_type(4))) float;
using u16x4  = __attribute__((ext_vector_type(4))) unsigned short;

#define MFMA16(A,B,C) __builtin_amdgcn_mfma_f32_16x16x32_bf16((A),(B),(C),0,0,0)

#if __has_builtin(__builtin_amdgcn_exp2f)
#define EXP2(x) __builtin_amdgcn_exp2f(x)
#else
#define EXP2(x) exp2f(x)
#endif

__device__ __forceinline__ unsigned short f2b(float f) {
  unsigned u = __float_as_uint(f);
  return (unsigned short)((u + 0x7fffu + ((u >> 16) & 1u)) >> 16);  // RNE
}
__device__ __forceinline__ short8 mk8(unsigned a, unsigned b, unsigned c, unsigned d) {
  union { unsigned u[4]; short8 s; } t; t.u[0]=a; t.u[1]=b; t.u[2]=c; t.u[3]=d; return t.s;
}
// trunc-pack two f32 -> bf16x2 (low = lo, high = hi), 1 VALU op.
// v_perm selector: bytes 0-3 pick src1, 4-7 pick src0 -> 0x07060302 = [s1.hi16, s0.hi16]
__device__ __forceinline__ unsigned pk2(float lo, float hi) {
  return __builtin_amdgcn_perm(__float_as_uint(hi), __float_as_uint(lo), 0x07060302u);
}
// 8 consecutive f32 -> bf16x8 fragment (optional scale, pure VALU, RNE)
__device__ __forceinline__ short8 w8s(const float* p, float s) {
  const f32x4* q = (const f32x4*)p;
  f32x4 a = q[0], b = q[1];
  short8 r;
  r[0]=(short)f2b(a[0]*s); r[1]=(short)f2b(a[1]*s); r[2]=(short)f2b(a[2]*s); r[3]=(short)f2b(a[3]*s);
  r[4]=(short)f2b(b[0]*s); r[5]=(short)f2b(b[1]*s); r[6]=(short)f2b(b[2]*s); r[7]=(short)f2b(b[3]*s);
  return r;
}

// T=512, N=128, D=64, H=4, HID=OUT=64

// ---------------- kernel 1: xin = x + pe, transpose to [n][t][d] bf16 (r7-exact) ----------------
__global__ void prep_kernel(const float* __restrict__ x, const float* __restrict__ pe,
                            unsigned* __restrict__ xinT) {
  int i2 = blockIdx.x * 256 + threadIdx.x;
  const float2* xp = (const float2*)x;
  const float2* pp = (const float2*)pe;
  float2 a = xp[i2], b = pp[i2];
  float s0 = a.x + b.x, s1 = a.y + b.y;
  int i = i2 << 1;
  int t = i >> 13, rem = i & 8191, n = rem >> 6, d = rem & 63;
  unsigned v = (unsigned)f2b(s0) | ((unsigned)f2b(s1) << 16);
  xinT[((n * 512 + t) * 64 + d) >> 1] = v;
}

// ---------------- attn building blocks ----------------
__device__ __forceinline__ void load_aK(const unsigned short* sK, int kb, int lg, int lm,
                                        short8 (&aK)[2][2]) {
#pragma unroll
  for (int km = 0; km < 2; ++km)
#pragma unroll
    for (int ks = 0; ks < 2; ++ks) {
      int row = kb + km * 16 + lm;
      aK[km][ks] = *(const short8*)&sK[row * 64 + ((ks * 32 + lg * 8) ^ ((row & 7) << 3))];
    }
}

// one 32-key slab: S^T MFMA -> mask -> exp2 -> trunc-pack -> ls/PV MFMA
__device__ __forceinline__ void process_slab(
    const short8 (&aK)[2][2], const short8* sVf, int kb, bool diag,
    const short8 (&qB)[2][2], f32x4 (&oAcc)[2][4], f32x4 (&lsAcc)[2],
    const short8 ones, int lg, int lm, int l) {
  const f32x4 zero4 = {0.f, 0.f, 0.f, 0.f};
  // vB loads issue early; first use is ~S+exp later
  short8 vB[4];
#pragma unroll
  for (int ot = 0; ot < 4; ++ot) vB[ot] = sVf[(((kb >> 5) * 4) + ot) * 64 + l];
  f32x4 st[2][2];
#pragma unroll
  for (int km = 0; km < 2; ++km)
#pragma unroll
    for (int qn = 0; qn < 2; ++qn) {
      f32x4 a = zero4;
      a = MFMA16(aK[km][0], qB[qn][0], a);
      a = MFMA16(aK[km][1], qB[qn][1], a);
      st[km][qn] = a;
    }
  if (diag) {   // causal mask -> exp2(-1e30) = 0
#pragma unroll
    for (int km = 0; km < 2; ++km)
#pragma unroll
      for (int qn = 0; qn < 2; ++qn)
#pragma unroll
        for (int r = 0; r < 4; ++r) {
          int key = km * 16 + lg * 4 + r, qr = qn * 16 + lm;
          if (key > qr) st[km][qn][r] = -1e30f;
        }
  }
#pragma unroll
  for (int km = 0; km < 2; ++km)
#pragma unroll
    for (int qn = 0; qn < 2; ++qn)
#pragma unroll
      for (int r = 0; r < 4; ++r) st[km][qn][r] = EXP2(st[km][qn][r]);
#pragma unroll
  for (int mo = 0; mo < 2; ++mo) {
    short8 pA = mk8(pk2(st[0][mo][0], st[0][mo][1]), pk2(st[0][mo][2], st[0][mo][3]),
                    pk2(st[1][mo][0], st[1][mo][1]), pk2(st[1][mo][2], st[1][mo][3]));
    lsAcc[mo] = MFMA16(pA, ones, lsAcc[mo]);     // row-sum of the SAME truncated P
#pragma unroll
    for (int ot = 0; ot < 4; ++ot) oAcc[mo][ot] = MFMA16(pA, vB[ot], oAcc[mo][ot]);
  }
}

// ---------------- kernel 2: fused QKV + causal flash attention ----------------
// r7 skeleton (512 thr, 8 waves, 144 KiB LDS, chunks {w, 15-w}) + three deltas:
//  (1) ls via ones-MFMA (lane-local normalize, zero epilogue shuffles)
//  (2) P packed by v_perm trunc (1 op / 2 elems); ls sums the same truncated P
//  (3) aK double-buffered ping-pong across slabs (static indexing)
__global__ __launch_bounds__(512) void attn_kernel(
    const unsigned short* __restrict__ xinT,
    const float* __restrict__ wq, const float* __restrict__ wk,
    const float* __restrict__ wv, unsigned short* __restrict__ heads) {
  __shared__ unsigned short sK[512 * 64];       // 64 KiB, XOR-swizzled
  __shared__ short8 sVf[16 * 4 * 64];           // 64 KiB kappa2 V fragments
  __shared__ unsigned short sS[8][16 * 64];     // 16 KiB per-wave scratch

  const int hn = blockIdx.x;
  const int h  = hn & 3;
  const int n  = hn >> 2;
  const int w  = threadIdx.x >> 6;    // 0..7
  const int l  = threadIdx.x & 63;
  const int lg = l >> 4;
  const int lm = l & 15;

  const unsigned short* xn = xinT + n * (512 * 64);
  const f32x4 zero4 = {0.f, 0.f, 0.f, 0.f};
  const float SC = 0.18033688011112042f;   // (1/sqrt(64)) * log2(e)
  const short8 ones = mk8(0x3F803F80u, 0x3F803F80u, 0x3F803F80u, 0x3F803F80u);

  // ---- stage K (swizzled) and V (kappa2 fragments); wave w: slabs {2w, 2w+1} (r7-exact) ----
  {
    short8 wkB[4][2], wvB[4][2];
    const float* bk = wk + h * 64 * 64;
    const float* bv = wv + h * 64 * 64;
#pragma unroll
    for (int nt = 0; nt < 4; ++nt)
#pragma unroll
      for (int ks = 0; ks < 2; ++ks) {
        int off = (nt * 16 + lm) * 64 + ks * 32 + lg * 8;
        wkB[nt][ks] = w8s(bk + off, 1.0f);
        wvB[nt][ks] = w8s(bv + off, 1.0f);
      }
#pragma unroll
    for (int j = 0; j < 2; ++j) {
      int slab = w * 2 + j;
      int s0 = slab * 32;
      short8 aX[2][2];
#pragma unroll
      for (int km = 0; km < 2; ++km) {
        aX[km][0] = *(const short8*)(xn + (s0 + km * 16 + lm) * 64 + lg * 8);
        aX[km][1] = *(const short8*)(xn + (s0 + km * 16 + lm) * 64 + 32 + lg * 8);
      }
#pragma unroll
      for (int nt = 0; nt < 4; ++nt) {
        f32x4 k0 = zero4, k1 = zero4, v0 = zero4, v1 = zero4;
        k0 = MFMA16(aX[0][0], wkB[nt][0], k0); k0 = MFMA16(aX[0][1], wkB[nt][1], k0);
        k1 = MFMA16(aX[1][0], wkB[nt][0], k1); k1 = MFMA16(aX[1][1], wkB[nt][1], k1);
        v0 = MFMA16(aX[0][0], wvB[nt][0], v0); v0 = MFMA16(aX[0][1], wvB[nt][1], v0);
        v1 = MFMA16(aX[1][0], wvB[nt][0], v1); v1 = MFMA16(aX[1][1], wvB[nt][1], v1);
#pragma unroll
        for (int r = 0; r < 4; ++r) {
          int row0 = s0 + lg * 4 + r;
          int row1 = s0 + 16 + lg * 4 + r;
          int e    = nt * 16 + lm;
          sK[row0 * 64 + (e ^ ((row0 & 7) << 3))] = f2b(k0[r]);
          sK[row1 * 64 + (e ^ ((row1 & 7) << 3))] = f2b(k1[r]);
        }
        short8 vv;
        vv[0]=(short)f2b(v0[0]); vv[1]=(short)f2b(v0[1]);
        vv[2]=(short)f2b(v0[2]); vv[3]=(short)f2b(v0[3]);
        vv[4]=(short)f2b(v1[0]); vv[5]=(short)f2b(v1[1]);
        vv[6]=(short)f2b(v1[2]); vv[7]=(short)f2b(v1[3]);
        sVf[(slab * 4 + nt) * 64 + l] = vv;
      }
    }
  }
  __syncthreads();   // K and V staged

  unsigned short* sQw = sS[w];

  // chunk map: wave w handles {w, 15-w} -> 17 slabs each
  for (int c = 0; c < 2; ++c) {
    const int chunk = c ? (15 - w) : w;
    const int qb = chunk * 32;

    // ---- Q projection (wqB scoped per chunk to cap slab-loop pressure) ----
    short8 qB[2][2];
    {
      short8 wqB[4][2];
      const float* bq = wq + h * 64 * 64;
#pragma unroll
      for (int nt = 0; nt < 4; ++nt)
#pragma unroll
        for (int ks = 0; ks < 2; ++ks)
          wqB[nt][ks] = w8s(bq + (nt * 16 + lm) * 64 + ks * 32 + lg * 8, SC);
#pragma unroll
      for (int mt = 0; mt < 2; ++mt) {
        int r0 = qb + mt * 16;
        short8 aX0 = *(const short8*)(xn + (r0 + lm) * 64 + lg * 8);
        short8 aX1 = *(const short8*)(xn + (r0 + lm) * 64 + 32 + lg * 8);
#pragma unroll
        for (int nt = 0; nt < 4; ++nt) {
          f32x4 acc = zero4;
          acc = MFMA16(aX0, wqB[nt][0], acc);
          acc = MFMA16(aX1, wqB[nt][1], acc);
#pragma unroll
          for (int r = 0; r < 4; ++r) {
            int qr = lg * 4 + r;
            int e  = nt * 16 + lm;
            sQw[qr * 64 + (e ^ ((qr & 7) << 3))] = f2b(acc[r]);
          }
        }
#pragma unroll
        for (int ks = 0; ks < 2; ++ks)
          qB[mt][ks] = *(const short8*)&sQw[lm * 64 + ((ks * 32 + lg * 8) ^ ((lm & 7) << 3))];
      }
    }

    f32x4 oAcc[2][4];
#pragma unroll
    for (int mo = 0; mo < 2; ++mo)
#pragma unroll
      for (int ot = 0; ot < 4; ++ot) oAcc[mo][ot] = zero4;
    f32x4 lsAcc[2] = {zero4, zero4};

    // ---- pipelined slab loop: aK ping-pong, next loads overlap current compute ----
    short8 aKa[2][2], aKb[2][2];
    load_aK(sK, 0, lg, lm, aKa);
    int kb = 0;
    while (true) {
      if (kb < qb) load_aK(sK, kb + 32, lg, lm, aKb);
      process_slab(aKa, sVf, kb, kb == qb, qB, oAcc, lsAcc, ones, lg, lm, l);
      if (kb >= qb) break;
      kb += 32;
      if (kb < qb) load_aK(sK, kb + 32, lg, lm, aKa);
      process_slab(aKb, sVf, kb, kb == qb, qB, oAcc, lsAcc, ones, lg, lm, l);
      if (kb >= qb) break;
      kb += 32;
    }

    // ---- epilogue: lane-local normalize (lsAcc rows == oAcc rows), transpose, store ----
#pragma unroll
    for (int mo = 0; mo < 2; ++mo) {
      float li[4];
#pragma unroll
      for (int r = 0; r < 4; ++r) li[r] = 1.0f / lsAcc[mo][r];
#pragma unroll
      for (int ot = 0; ot < 4; ++ot)
#pragma unroll
        for (int r = 0; r < 4; ++r) {
          int qr = lg * 4 + r;
          int e  = ot * 16 + lm;
          sQw[qr * 64 + (e ^ ((qr & 7) << 3))] = f2b(oAcc[mo][ot][r] * li[r]);
        }
#pragma unroll
      for (int j2 = 0; j2 < 4; ++j2) {
        int tl = j2 * 4 + lg;
        int ob = lm * 4;
        u16x4 v = *(const u16x4*)&sQw[tl * 64 + (ob ^ ((tl & 7) << 3))];
        int t = qb + mo * 16 + tl;
        *(u16x4*)&heads[(t * 128 + n) * 256 + h * 64 + ob] = v;
      }
    }
  }
}

// ---------------- kernel 3: out = heads[65536,256] @ wo^T (r7-exact) ----------------
__global__ __launch_bounds__(256) void outproj_kernel(
    const unsigned short* __restrict__ heads,
    const float* __restrict__ wo,
    float* __restrict__ out) {
  const int w  = threadIdx.x >> 6;
  const int l  = threadIdx.x & 63;
  const int lg = l >> 4, lm = l & 15;
  const f32x4 zero4 = {0.f, 0.f, 0.f, 0.f};

  short8 woB[4][8];
#pragma unroll
  for (int nt = 0; nt < 4; ++nt)
#pragma unroll
    for (int ks = 0; ks < 8; ++ks)
      woB[nt][ks] = w8s(wo + (nt * 16 + lm) * 256 + ks * 32 + lg * 8, 1.0f);

  const int wid = blockIdx.x * 4 + w;
  for (int it = 0; it < 2; ++it) {
    int r0 = (wid * 2 + it) * 16;
    f32x4 acc[4];
#pragma unroll
    for (int nt = 0; nt < 4; ++nt) acc[nt] = zero4;
#pragma unroll
    for (int ks = 0; ks < 8; ++ks) {
      short8 aF = *(const short8*)&heads[(r0 + lm) * 256 + ks * 32 + lg * 8];
#pragma unroll
      for (int nt = 0; nt < 4; ++nt)
        acc[nt] = MFMA16(aF, woB[nt][ks], acc[nt]);
    }
#pragma unroll
    for (int nt = 0; nt < 4; ++nt)
#pragma unroll
      for (int r = 0; r < 4; ++r)
        out[(r0 + lg * 4 + r) * 64 + nt * 16 + lm] = acc[nt][r];
  }
}

// ---------------- launch (r7-exact ws layout) ----------------
extern "C" void kernel_launch(void* const* d_in, const int* in_sizes, int n_in,
                              void* d_out, int out_size, void* d_ws, size_t ws_size,
                              hipStream_t stream) {
  const float* x  = (const float*)d_in[0];
  const float* pe = (const float*)d_in[1];
  const float* wq = (const float*)d_in[2];
  const float* wk = (const float*)d_in[3];
  const float* wv = (const float*)d_in[4];
  const float* wo = (const float*)d_in[5];

  unsigned short* xinT  = (unsigned short*)d_ws;                          // 8 MiB  [n][t][d]
  unsigned short* heads = (unsigned short*)((char*)d_ws + (16u << 20));   // 32 MiB [t][n][256]

  prep_kernel<<<8192, 256, 0, stream>>>(x, pe, (unsigned*)xinT);
  attn_kernel<<<512, 512, 0, stream>>>(xinT, wq, wk, wv, heads);
  outproj_kernel<<<512, 256, 0, stream>>>(heads, wo, (float*)d_out);
}